// Round 2
// baseline (252.819 us; speedup 1.0000x reference)
//
#include <hip/hip_runtime.h>
#include <math.h>

#define N_NODES 4096
#define DIM 256
#define MWORDS 128  // 4096 bits / 32

// ---------------------------------------------------------------------------
// Edge scatter -> dense bitmask (dedups duplicate edges, matches bool-mask
// semantics of the reference). edge_index arrives as int32 ([2, E] flat).
// ---------------------------------------------------------------------------
__global__ void build_mask_kernel(const int* __restrict__ ei,
                                  unsigned int* __restrict__ mask, int E) {
  int e = blockIdx.x * blockDim.x + threadIdx.x;
  if (e >= E) return;
  int r = ei[e];       // destination (row of scores)
  int c = ei[E + e];   // source      (col of scores)
  atomicOr(&mask[(size_t)r * MWORDS + (c >> 5)], 1u << (c & 31));
}

// ---------------------------------------------------------------------------
// Generic f32 GEMM: C[M,N=256] = A[M,256] @ B[256,256] + bias, tiled 64x64.
// EPI 0: bias only
// EPI 1: bias + eps * X   (out-projection residual term)
// EPI 2: A-side transform a' = relu(a*scA[k] + shA[k]) (fused BN1+ReLU)
// ---------------------------------------------------------------------------
#define BM 64
#define BN 64
#define BK 32

template <int EPI>
__launch_bounds__(256)
__global__ void gemm_f32(const float* __restrict__ A, const float* __restrict__ B,
                         const float* __restrict__ bias, float* __restrict__ C,
                         int K, int ldc,
                         const float* __restrict__ X, const float* __restrict__ epsp,
                         const float* __restrict__ scA, const float* __restrict__ shA) {
  __shared__ float As[BK][BM + 4];  // stored transposed: As[k][m]
  __shared__ float Bs[BK][BN + 4];

  const int tid = threadIdx.x;
  const int tx = tid & 15;   // N direction
  const int ty = tid >> 4;   // M direction
  const int m0 = blockIdx.y * BM;
  const int n0 = blockIdx.x * BN;

  // A tile load: 64 rows x 32 k = 512 float4, 2 per thread
  const int arow = tid >> 2;
  const int ac   = (tid & 3) * 4;
  // B tile load: 32 rows x 64 n = 512 float4, 2 per thread
  const int brow = tid >> 4;
  const int bcol = tx * 4;

  float acc[4][4] = {};

  for (int kt = 0; kt < K; kt += BK) {
    float4 a0 = *(const float4*)(A + (size_t)(m0 + arow) * K + kt + ac);
    float4 a1 = *(const float4*)(A + (size_t)(m0 + arow) * K + kt + ac + 16);
    const float4 b0 = *(const float4*)(B + (size_t)(kt + brow) * DIM + n0 + bcol);
    const float4 b1 = *(const float4*)(B + (size_t)(kt + brow + 16) * DIM + n0 + bcol);

    if (EPI == 2) {  // fused BN+ReLU on the A operand (per-K-column affine)
      const int k0 = kt + ac;
      const int k1 = k0 + 16;
      a0.x = fmaxf(fmaf(a0.x, scA[k0 + 0], shA[k0 + 0]), 0.f);
      a0.y = fmaxf(fmaf(a0.y, scA[k0 + 1], shA[k0 + 1]), 0.f);
      a0.z = fmaxf(fmaf(a0.z, scA[k0 + 2], shA[k0 + 2]), 0.f);
      a0.w = fmaxf(fmaf(a0.w, scA[k0 + 3], shA[k0 + 3]), 0.f);
      a1.x = fmaxf(fmaf(a1.x, scA[k1 + 0], shA[k1 + 0]), 0.f);
      a1.y = fmaxf(fmaf(a1.y, scA[k1 + 1], shA[k1 + 1]), 0.f);
      a1.z = fmaxf(fmaf(a1.z, scA[k1 + 2], shA[k1 + 2]), 0.f);
      a1.w = fmaxf(fmaf(a1.w, scA[k1 + 3], shA[k1 + 3]), 0.f);
    }

    __syncthreads();  // previous iteration's reads complete
    As[ac + 0][arow] = a0.x;
    As[ac + 1][arow] = a0.y;
    As[ac + 2][arow] = a0.z;
    As[ac + 3][arow] = a0.w;
    As[ac + 16][arow] = a1.x;
    As[ac + 17][arow] = a1.y;
    As[ac + 18][arow] = a1.z;
    As[ac + 19][arow] = a1.w;
    *(float4*)&Bs[brow][bcol] = b0;
    *(float4*)&Bs[brow + 16][bcol] = b1;
    __syncthreads();

#pragma unroll
    for (int k = 0; k < BK; ++k) {
      const float4 av = *(const float4*)&As[k][ty * 4];
      const float4 bv = *(const float4*)&Bs[k][tx * 4];
      const float a[4] = {av.x, av.y, av.z, av.w};
      const float b[4] = {bv.x, bv.y, bv.z, bv.w};
#pragma unroll
      for (int i = 0; i < 4; ++i)
#pragma unroll
        for (int j = 0; j < 4; ++j) acc[i][j] = fmaf(a[i], b[j], acc[i][j]);
    }
  }

  const int col = n0 + tx * 4;
  const float bias4[4] = {bias[col], bias[col + 1], bias[col + 2], bias[col + 3]};
  float ev = 0.f;
  if (EPI == 1) ev = epsp[0];
#pragma unroll
  for (int i = 0; i < 4; ++i) {
    const int row = m0 + ty * 4 + i;
    float4 o;
    o.x = acc[i][0] + bias4[0];
    o.y = acc[i][1] + bias4[1];
    o.z = acc[i][2] + bias4[2];
    o.w = acc[i][3] + bias4[3];
    if (EPI == 1) {
      const float4 xv = *(const float4*)(X + (size_t)row * DIM + col);
      o.x = fmaf(ev, xv.x, o.x);
      o.y = fmaf(ev, xv.y, o.y);
      o.z = fmaf(ev, xv.z, o.z);
      o.w = fmaf(ev, xv.w, o.w);
    }
    *(float4*)(C + (size_t)row * ldc + col) = o;
  }
}

// ---------------------------------------------------------------------------
// Sparse flash-style attention. One wave per destination row.
// QKV layout: [4096][768] with Q = cols 0-255, K = 256-511, V = 512-767.
// Lane l holds elements [4l,4l+3]; lanes 0-31 = head 0, lanes 32-63 = head 1.
// Per-head dot via shuffle reduction within each 32-lane half (xor offsets
// 1..16 stay inside the half).
// ---------------------------------------------------------------------------
__launch_bounds__(256)
__global__ void attn_kernel(const float* __restrict__ qkv,
                            const unsigned int* __restrict__ mask,
                            float* __restrict__ vagg) {
  const int wave = threadIdx.x >> 6;
  const int lane = threadIdx.x & 63;
  const int r = blockIdx.x * 4 + wave;

  float4 q = *(const float4*)(qkv + (size_t)r * 768 + lane * 4);
  const float sc = 0.088388347648318447f;  // 1/sqrt(128)
  q.x *= sc; q.y *= sc; q.z *= sc; q.w *= sc;

  float4 acc = make_float4(0.f, 0.f, 0.f, 0.f);
  float m = -INFINITY;
  float lsum = 0.f;

  const unsigned int* mrow = mask + (size_t)r * MWORDS;
  for (int wi = 0; wi < MWORDS; ++wi) {
    unsigned int bits = mrow[wi];
    while (bits) {
      const int b = __ffs(bits) - 1;
      bits &= bits - 1;
      const int c = wi * 32 + b;
      const float* crow = qkv + (size_t)c * 768;
      const float4 kf = *(const float4*)(crow + 256 + lane * 4);
      const float4 vf = *(const float4*)(crow + 512 + lane * 4);
      float d = q.x * kf.x + q.y * kf.y + q.z * kf.z + q.w * kf.w;
      d += __shfl_xor(d, 16);
      d += __shfl_xor(d, 8);
      d += __shfl_xor(d, 4);
      d += __shfl_xor(d, 2);
      d += __shfl_xor(d, 1);
      const float mnew = fmaxf(m, d);
      const float p = __expf(d - mnew);
      const float resc = __expf(m - mnew);  // exp(-inf)=0 handles first iter
      lsum = lsum * resc + p;
      acc.x = acc.x * resc + p * vf.x;
      acc.y = acc.y * resc + p * vf.y;
      acc.z = acc.z * resc + p * vf.z;
      acc.w = acc.w * resc + p * vf.w;
      m = mnew;
    }
  }
  const float inv = 1.f / lsum;
  float4 o = make_float4(acc.x * inv, acc.y * inv, acc.z * inv, acc.w * inv);
  *(float4*)(vagg + (size_t)r * DIM + lane * 4) = o;
}

// ---------------------------------------------------------------------------
// Column statistics for BatchNorm (sum / sum of squares), coalesced:
// thread t owns column t, each block strides 256 rows, atomicAdd partials.
// ---------------------------------------------------------------------------
__launch_bounds__(256)
__global__ void colstats_kernel(const float* __restrict__ H, float* __restrict__ sum,
                                float* __restrict__ sumsq) {
  const int c = threadIdx.x;
  const int r0 = blockIdx.x * 256;
  float s = 0.f, qq = 0.f;
  for (int r = r0; r < r0 + 256; ++r) {
    const float v = H[(size_t)r * DIM + c];
    s += v;
    qq = fmaf(v, v, qq);
  }
  atomicAdd(&sum[c], s);
  atomicAdd(&sumsq[c], qq);
}

__global__ void bn_finalize_kernel(const float* __restrict__ sum,
                                   const float* __restrict__ sumsq,
                                   const float* __restrict__ g,
                                   const float* __restrict__ be,
                                   float* __restrict__ scale,
                                   float* __restrict__ shift) {
  const int c = threadIdx.x;
  const float invn = 1.f / (float)N_NODES;
  const float mu = sum[c] * invn;
  const float var = sumsq[c] * invn - mu * mu;  // biased variance (ddof=0)
  const float s = g[c] * rsqrtf(var + 1e-5f);
  scale[c] = s;
  shift[c] = fmaf(-mu, s, be[c]);
}

__launch_bounds__(256)
__global__ void bn_apply_kernel(const float* __restrict__ H,
                                const float* __restrict__ scale,
                                const float* __restrict__ shift,
                                float* __restrict__ out) {
  const int i = blockIdx.x * 256 + threadIdx.x;  // float4 index
  const float4 h = ((const float4*)H)[i];
  const int c = (i * 4) & (DIM - 1);
  float4 o;
  o.x = fmaxf(fmaf(h.x, scale[c + 0], shift[c + 0]), 0.f);
  o.y = fmaxf(fmaf(h.y, scale[c + 1], shift[c + 1]), 0.f);
  o.z = fmaxf(fmaf(h.z, scale[c + 2], shift[c + 2]), 0.f);
  o.w = fmaxf(fmaf(h.w, scale[c + 3], shift[c + 3]), 0.f);
  ((float4*)out)[i] = o;
}

// ---------------------------------------------------------------------------
extern "C" void kernel_launch(void* const* d_in, const int* in_sizes, int n_in,
                              void* d_out, int out_size, void* d_ws, size_t ws_size,
                              hipStream_t stream) {
  const float* x   = (const float*)d_in[0];
  const int*   ei  = (const int*)d_in[1];   // int32! (JAX x64 disabled)
  const float* wq  = (const float*)d_in[2];
  const float* bq  = (const float*)d_in[3];
  const float* wk  = (const float*)d_in[4];
  const float* bk  = (const float*)d_in[5];
  const float* wv  = (const float*)d_in[6];
  const float* bv  = (const float*)d_in[7];
  const float* wo  = (const float*)d_in[8];
  const float* bo  = (const float*)d_in[9];
  const float* eps = (const float*)d_in[10];
  const float* w1  = (const float*)d_in[11];
  const float* b1  = (const float*)d_in[12];
  const float* g1  = (const float*)d_in[13];
  const float* be1 = (const float*)d_in[14];
  const float* w2  = (const float*)d_in[15];
  const float* b2  = (const float*)d_in[16];
  const float* g2  = (const float*)d_in[17];
  const float* be2 = (const float*)d_in[18];
  float* out = (float*)d_out;

  char* ws = (char*)d_ws;
  unsigned int* mask = (unsigned int*)ws;                         // 2 MB
  float* qkv  = (float*)(ws + (size_t)(2 << 20));                 // 12 MB [4096][768]
  float* vagg = qkv + (size_t)N_NODES * 768;
  float* a1   = vagg + (size_t)N_NODES * DIM;
  float* h1   = a1 + (size_t)N_NODES * DIM;
  float* h2   = h1 + (size_t)N_NODES * DIM;
  float* stats = h2 + (size_t)N_NODES * DIM;
  float* sum1 = stats;
  float* sq1  = stats + 256;
  float* sum2 = stats + 512;
  float* sq2  = stats + 768;
  float* sc1  = stats + 1024;
  float* sh1  = stats + 1280;
  float* sc2  = stats + 1536;
  float* sh2  = stats + 1792;

  const int E = in_sizes[1] / 2;

  hipMemsetAsync(mask, 0, (size_t)N_NODES * MWORDS * sizeof(unsigned int), stream);
  hipMemsetAsync(stats, 0, 1024 * sizeof(float), stream);
  build_mask_kernel<<<(E + 255) / 256, 256, 0, stream>>>(ei, mask, E);

  dim3 gg(DIM / BN, N_NODES / BM);
  // QKV projections into [4096][768]
  gemm_f32<0><<<gg, 256, 0, stream>>>(x, wq, bq, qkv + 0,   256, 768, nullptr, nullptr, nullptr, nullptr);
  gemm_f32<0><<<gg, 256, 0, stream>>>(x, wk, bk, qkv + 256, 256, 768, nullptr, nullptr, nullptr, nullptr);
  gemm_f32<0><<<gg, 256, 0, stream>>>(x, wv, bv, qkv + 512, 256, 768, nullptr, nullptr, nullptr, nullptr);

  attn_kernel<<<N_NODES / 4, 256, 0, stream>>>(qkv, mask, vagg);

  // out-projection + eps*x residual
  gemm_f32<1><<<gg, 256, 0, stream>>>(vagg, wo, bo, a1, 256, 256, x, eps, nullptr, nullptr);
  // MLP layer 1 pre-activation
  gemm_f32<0><<<gg, 256, 0, stream>>>(a1, w1, b1, h1, 256, 256, nullptr, nullptr, nullptr, nullptr);
  colstats_kernel<<<16, 256, 0, stream>>>(h1, sum1, sq1);
  bn_finalize_kernel<<<1, 256, 0, stream>>>(sum1, sq1, g1, be1, sc1, sh1);
  // MLP layer 2 with fused BN1+ReLU on the A operand
  gemm_f32<2><<<gg, 256, 0, stream>>>(h1, w2, b2, h2, 256, 256, nullptr, nullptr, sc1, sh1);
  colstats_kernel<<<16, 256, 0, stream>>>(h2, sum2, sq2);
  bn_finalize_kernel<<<1, 256, 0, stream>>>(sum2, sq2, g2, be2, sc2, sh2);
  // final BN2 + ReLU -> output
  bn_apply_kernel<<<(N_NODES * DIM / 4) / 256, 256, 0, stream>>>(h2, sc2, sh2, out);
}

// Round 3
// 180.066 us; speedup vs baseline: 1.4040x; 1.4040x over previous
//
#include <hip/hip_runtime.h>
#include <math.h>

#define N_NODES 4096
#define DIM 256
#define GK 256        // all GEMM K dims are 256
#define MWORDS 128    // 4096 bits / 32
#define MAXNBR 192    // max in-degree bound (mean 33, std ~5.6)

typedef float f32x4 __attribute__((ext_vector_type(4)));
typedef short s16x8 __attribute__((ext_vector_type(8)));
typedef short s16x4 __attribute__((ext_vector_type(4)));

__device__ __forceinline__ unsigned short bf16_rne(float f) {
  unsigned int u = __float_as_uint(f);
  u += 0x7FFFu + ((u >> 16) & 1u);
  return (unsigned short)(u >> 16);
}

__device__ __forceinline__ void split_bf16(float f, short& hi, short& lo) {
  unsigned short h = bf16_rne(f);
  float hf = __uint_as_float(((unsigned int)h) << 16);
  hi = (short)h;
  lo = (short)bf16_rne(f - hf);
}

// ---------------------------------------------------------------------------
// Edge scatter -> dense bitmask (dedups duplicate edges). edge_index = int32.
// ---------------------------------------------------------------------------
__global__ void build_mask_kernel(const int* __restrict__ ei,
                                  unsigned int* __restrict__ mask, int E) {
  int e = blockIdx.x * blockDim.x + threadIdx.x;
  if (e >= E) return;
  int r = ei[e];       // destination row
  int c = ei[E + e];   // source col
  atomicOr(&mask[(size_t)r * MWORDS + (c >> 5)], 1u << (c & 31));
}

// ---------------------------------------------------------------------------
// Weight prep: W[k][n] f32 -> Wt_hi/Wt_lo[n][k] bf16 (hi/lo split), with QKV
// packed at rows 0..767, wo at 768, w1 at 1024, w2 at 1280. Also packs bqkv.
// Grid: 1536 blocks x 256 threads; block b: matrix b>>8, k-row b&255; t = n.
// ---------------------------------------------------------------------------
__global__ void prep_weights(const float* __restrict__ wq, const float* __restrict__ wk,
                             const float* __restrict__ wv, const float* __restrict__ wo,
                             const float* __restrict__ w1, const float* __restrict__ w2,
                             const float* __restrict__ bq, const float* __restrict__ bk,
                             const float* __restrict__ bv,
                             short* __restrict__ wt_hi, short* __restrict__ wt_lo,
                             float* __restrict__ bqkv) {
  const int b = blockIdx.x;
  const int t = threadIdx.x;
  const int mat = b >> 8;
  const int k = b & 255;
  const float* src = (mat == 0) ? wq : (mat == 1) ? wk : (mat == 2) ? wv
                   : (mat == 3) ? wo : (mat == 4) ? w1 : w2;
  const float v = src[(size_t)k * 256 + t];
  short hi, lo;
  split_bf16(v, hi, lo);
  const int nbase = (mat < 3) ? mat * 256 : 768 + (mat - 3) * 256;
  const size_t idx = (size_t)(nbase + t) * GK + k;
  wt_hi[idx] = hi;
  wt_lo[idx] = lo;
  if (k == 0 && mat < 3)
    bqkv[mat * 256 + t] = (mat == 0 ? bq : mat == 1 ? bk : bv)[t];
}

// ---------------------------------------------------------------------------
// MFMA GEMM: C[M=4096, N] = A[M,256] @ W[256,N] + bias, via bf16 hi/lo split
// (3 MFMA terms: hh + hl + lh -> ~1e-5 relative error, near-f32).
// Block: 256 threads = 4 waves (2x2 over 64x64 tile, 32x32 per wave).
// B operand pre-transposed/split: Wt_hi/Wt_lo[n][k] bf16.
// EPI 0: bias only
// EPI 1: bias + eps * X (residual)
// EPI 2: A-side transform a' = relu(a*scA[k] + shA[k]) (fused BN+ReLU)
// ---------------------------------------------------------------------------
template <int EPI>
__launch_bounds__(256)
__global__ void gemm_mfma(const float* __restrict__ A,
                          const short* __restrict__ Wt_hi,
                          const short* __restrict__ Wt_lo,
                          const float* __restrict__ bias,
                          float* __restrict__ C, int ldc,
                          const float* __restrict__ X,
                          const float* __restrict__ epsp,
                          const float* __restrict__ scA,
                          const float* __restrict__ shA) {
  __shared__ short As_hi[64][72], As_lo[64][72];  // pitch 144B (16B-aligned)
  __shared__ short Bs_hi[64][72], Bs_lo[64][72];

  const int tid = threadIdx.x;
  const int lane = tid & 63;
  const int wave = tid >> 6;
  const int wr = wave >> 1, wc = wave & 1;
  const int m0 = blockIdx.y * 64;
  const int n0 = blockIdx.x * 64;

  const int l15 = lane & 15;
  const int lg = lane >> 4;  // 0..3

  f32x4 acc[2][2] = {};

  for (int kt = 0; kt < GK; kt += 64) {
    if (kt) __syncthreads();
    // ---- stage A: 64m x 64k f32 -> bf16 hi/lo (4 float4 per thread) ----
#pragma unroll
    for (int i = 0; i < 4; ++i) {
      const int row = (tid >> 4) + i * 16;
      const int kc = (tid & 15) * 4;
      float4 av = *(const float4*)(A + (size_t)(m0 + row) * GK + kt + kc);
      if (EPI == 2) {
        const float4 s4 = *(const float4*)(scA + kt + kc);
        const float4 h4 = *(const float4*)(shA + kt + kc);
        av.x = fmaxf(fmaf(av.x, s4.x, h4.x), 0.f);
        av.y = fmaxf(fmaf(av.y, s4.y, h4.y), 0.f);
        av.z = fmaxf(fmaf(av.z, s4.z, h4.z), 0.f);
        av.w = fmaxf(fmaf(av.w, s4.w, h4.w), 0.f);
      }
      short h0, l0, h1, l1, h2, l2, h3, l3;
      split_bf16(av.x, h0, l0);
      split_bf16(av.y, h1, l1);
      split_bf16(av.z, h2, l2);
      split_bf16(av.w, h3, l3);
      s16x4 hv = {h0, h1, h2, h3};
      s16x4 lv = {l0, l1, l2, l3};
      *(s16x4*)&As_hi[row][kc] = hv;
      *(s16x4*)&As_lo[row][kc] = lv;
    }
    // ---- stage B: 64n x 64k bf16 (2x 16B chunks per thread per term) ----
#pragma unroll
    for (int i = 0; i < 2; ++i) {
      const int row = (tid >> 3) + i * 32;
      const int kc = (tid & 7) * 8;
      s16x8 bh = *(const s16x8*)(Wt_hi + (size_t)(n0 + row) * GK + kt + kc);
      s16x8 bl = *(const s16x8*)(Wt_lo + (size_t)(n0 + row) * GK + kt + kc);
      *(s16x8*)&Bs_hi[row][kc] = bh;
      *(s16x8*)&Bs_lo[row][kc] = bl;
    }
    __syncthreads();
    // ---- MFMA: 2 k-chunks of 32, 2x2 fragments, 3 split terms ----
#pragma unroll
    for (int kk = 0; kk < 2; ++kk) {
      s16x8 ah[2], al[2], bh[2], bl[2];
#pragma unroll
      for (int f = 0; f < 2; ++f) {
        ah[f] = *(const s16x8*)&As_hi[wr * 32 + f * 16 + l15][kk * 32 + lg * 8];
        al[f] = *(const s16x8*)&As_lo[wr * 32 + f * 16 + l15][kk * 32 + lg * 8];
        bh[f] = *(const s16x8*)&Bs_hi[wc * 32 + f * 16 + l15][kk * 32 + lg * 8];
        bl[f] = *(const s16x8*)&Bs_lo[wc * 32 + f * 16 + l15][kk * 32 + lg * 8];
      }
#pragma unroll
      for (int fm = 0; fm < 2; ++fm)
#pragma unroll
        for (int fn = 0; fn < 2; ++fn) {
          acc[fm][fn] = __builtin_amdgcn_mfma_f32_16x16x32_bf16(ah[fm], bh[fn], acc[fm][fn], 0, 0, 0);
          acc[fm][fn] = __builtin_amdgcn_mfma_f32_16x16x32_bf16(ah[fm], bl[fn], acc[fm][fn], 0, 0, 0);
          acc[fm][fn] = __builtin_amdgcn_mfma_f32_16x16x32_bf16(al[fm], bh[fn], acc[fm][fn], 0, 0, 0);
        }
    }
  }

  // ---- epilogue: D layout col=lane&15, row=(lane>>4)*4+reg ----
  const float ev = (EPI == 1) ? epsp[0] : 0.f;
#pragma unroll
  for (int fm = 0; fm < 2; ++fm) {
    const int row0 = m0 + wr * 32 + fm * 16 + lg * 4;
#pragma unroll
    for (int fn = 0; fn < 2; ++fn) {
      const int col = n0 + wc * 32 + fn * 16 + l15;
      const float bb = bias[col];
#pragma unroll
      for (int j = 0; j < 4; ++j) {
        float v = acc[fm][fn][j] + bb;
        if (EPI == 1) v = fmaf(ev, X[(size_t)(row0 + j) * DIM + col], v);
        C[(size_t)(row0 + j) * ldc + col] = v;
      }
    }
  }
}

// ---------------------------------------------------------------------------
// Sparse attention, one wave per destination row.
// Phase 1: cooperative neighbor extraction (coalesced mask read + 64-lane
//          shfl prefix scan) into an LDS CSR list.
// Phase 2: batch-of-4 edge processing: 8 independent K/V float4 loads in
//          flight, 4 interleaved shuffle-reduce chains, one rescale / batch.
// Lanes 0-31 = head 0 (dims 0-127), lanes 32-63 = head 1.
// ---------------------------------------------------------------------------
__launch_bounds__(256)
__global__ void attn_kernel(const float* __restrict__ qkv,
                            const unsigned int* __restrict__ mask,
                            float* __restrict__ vagg) {
  __shared__ int nbr[4][MAXNBR];
  const int wave = threadIdx.x >> 6;
  const int lane = threadIdx.x & 63;
  const int r = blockIdx.x * 4 + wave;

  // ---- phase 1: extract neighbor list ----
  const unsigned int* mrow = mask + (size_t)r * MWORDS;
  int total = 0;
#pragma unroll
  for (int round = 0; round < 2; ++round) {
    unsigned int w = mrow[round * 64 + lane];
    const int cnt = __popc(w);
    int pre = cnt;
#pragma unroll
    for (int off = 1; off < 64; off <<= 1) {
      int t = __shfl_up(pre, off);
      if (lane >= off) pre += t;
    }
    const int wtot = __shfl(pre, 63);
    pre -= cnt;  // exclusive
    int base = total + pre;
    while (w) {
      const int b = __ffs(w) - 1;
      w &= w - 1;
      nbr[wave][base++] = (round * 64 + lane) * 32 + b;
    }
    total += wtot;
  }

  // ---- phase 2: online softmax over neighbor batches of 4 ----
  float4 q = *(const float4*)(qkv + (size_t)r * 768 + lane * 4);
  const float sc = 0.088388347648318447f;  // 1/sqrt(128)
  q.x *= sc; q.y *= sc; q.z *= sc; q.w *= sc;

  float4 acc = make_float4(0.f, 0.f, 0.f, 0.f);
  float m = -INFINITY, lsum = 0.f;
  const int* nb = nbr[wave];

  for (int i = 0; i < total; i += 4) {
    const int c0 = nb[i];
    const int c1 = (i + 1 < total) ? nb[i + 1] : -1;
    const int c2 = (i + 2 < total) ? nb[i + 2] : -1;
    const int c3 = (i + 3 < total) ? nb[i + 3] : -1;
    const float* p0 = qkv + (size_t)c0 * 768 + lane * 4;
    const float* p1 = qkv + (size_t)(c1 < 0 ? c0 : c1) * 768 + lane * 4;
    const float* p2 = qkv + (size_t)(c2 < 0 ? c0 : c2) * 768 + lane * 4;
    const float* p3 = qkv + (size_t)(c3 < 0 ? c0 : c3) * 768 + lane * 4;
    const float4 k0 = *(const float4*)(p0 + 256);
    const float4 k1 = *(const float4*)(p1 + 256);
    const float4 k2 = *(const float4*)(p2 + 256);
    const float4 k3 = *(const float4*)(p3 + 256);
    const float4 v0 = *(const float4*)(p0 + 512);
    const float4 v1 = *(const float4*)(p1 + 512);
    const float4 v2 = *(const float4*)(p2 + 512);
    const float4 v3 = *(const float4*)(p3 + 512);

    float d0 = q.x * k0.x + q.y * k0.y + q.z * k0.z + q.w * k0.w;
    float d1 = q.x * k1.x + q.y * k1.y + q.z * k1.z + q.w * k1.w;
    float d2 = q.x * k2.x + q.y * k2.y + q.z * k2.z + q.w * k2.w;
    float d3 = q.x * k3.x + q.y * k3.y + q.z * k3.z + q.w * k3.w;
#pragma unroll
    for (int s = 16; s >= 1; s >>= 1) {
      d0 += __shfl_xor(d0, s);
      d1 += __shfl_xor(d1, s);
      d2 += __shfl_xor(d2, s);
      d3 += __shfl_xor(d3, s);
    }
    if (c1 < 0) d1 = -INFINITY;
    if (c2 < 0) d2 = -INFINITY;
    if (c3 < 0) d3 = -INFINITY;
    const float mnew = fmaxf(fmaxf(fmaxf(d0, d1), fmaxf(d2, d3)), m);
    const float resc = __expf(m - mnew);  // first iter: exp(-inf)=0
    const float e0 = __expf(d0 - mnew);
    const float e1 = __expf(d1 - mnew);
    const float e2 = __expf(d2 - mnew);
    const float e3 = __expf(d3 - mnew);
    lsum = lsum * resc + ((e0 + e1) + (e2 + e3));
    acc.x = acc.x * resc + ((e0 * v0.x + e1 * v1.x) + (e2 * v2.x + e3 * v3.x));
    acc.y = acc.y * resc + ((e0 * v0.y + e1 * v1.y) + (e2 * v2.y + e3 * v3.y));
    acc.z = acc.z * resc + ((e0 * v0.z + e1 * v1.z) + (e2 * v2.z + e3 * v3.z));
    acc.w = acc.w * resc + ((e0 * v0.w + e1 * v1.w) + (e2 * v2.w + e3 * v3.w));
    m = mnew;
  }
  const float inv = 1.f / lsum;
  float4 o = make_float4(acc.x * inv, acc.y * inv, acc.z * inv, acc.w * inv);
  *(float4*)(vagg + (size_t)r * DIM + lane * 4) = o;
}

// ---------------------------------------------------------------------------
// BatchNorm column stats (sum / sumsq), 64 blocks x 64 rows, coalesced.
// ---------------------------------------------------------------------------
__launch_bounds__(256)
__global__ void colstats_kernel(const float* __restrict__ H, float* __restrict__ sum,
                                float* __restrict__ sumsq) {
  const int c = threadIdx.x;
  const int r0 = blockIdx.x * 64;
  float s = 0.f, qq = 0.f;
  for (int r = r0; r < r0 + 64; ++r) {
    const float v = H[(size_t)r * DIM + c];
    s += v;
    qq = fmaf(v, v, qq);
  }
  atomicAdd(&sum[c], s);
  atomicAdd(&sumsq[c], qq);
}

__global__ void bn_finalize_kernel(const float* __restrict__ sum,
                                   const float* __restrict__ sumsq,
                                   const float* __restrict__ g,
                                   const float* __restrict__ be,
                                   float* __restrict__ scale,
                                   float* __restrict__ shift) {
  const int c = threadIdx.x;
  const float invn = 1.f / (float)N_NODES;
  const float mu = sum[c] * invn;
  const float var = sumsq[c] * invn - mu * mu;  // biased variance
  const float s = g[c] * rsqrtf(var + 1e-5f);
  scale[c] = s;
  shift[c] = fmaf(-mu, s, be[c]);
}

__launch_bounds__(256)
__global__ void bn_apply_kernel(const float* __restrict__ H,
                                const float* __restrict__ scale,
                                const float* __restrict__ shift,
                                float* __restrict__ out) {
  const int i = blockIdx.x * 256 + threadIdx.x;  // float4 index
  const float4 h = ((const float4*)H)[i];
  const int c = (i * 4) & (DIM - 1);
  float4 o;
  o.x = fmaxf(fmaf(h.x, scale[c + 0], shift[c + 0]), 0.f);
  o.y = fmaxf(fmaf(h.y, scale[c + 1], shift[c + 1]), 0.f);
  o.z = fmaxf(fmaf(h.z, scale[c + 2], shift[c + 2]), 0.f);
  o.w = fmaxf(fmaf(h.w, scale[c + 3], shift[c + 3]), 0.f);
  ((float4*)out)[i] = o;
}

// ---------------------------------------------------------------------------
extern "C" void kernel_launch(void* const* d_in, const int* in_sizes, int n_in,
                              void* d_out, int out_size, void* d_ws, size_t ws_size,
                              hipStream_t stream) {
  const float* x   = (const float*)d_in[0];
  const int*   ei  = (const int*)d_in[1];   // int32 (JAX x64 disabled)
  const float* wq  = (const float*)d_in[2];
  const float* bq  = (const float*)d_in[3];
  const float* wk  = (const float*)d_in[4];
  const float* bk  = (const float*)d_in[5];
  const float* wv  = (const float*)d_in[6];
  const float* bv  = (const float*)d_in[7];
  const float* wo  = (const float*)d_in[8];
  const float* bo  = (const float*)d_in[9];
  const float* eps = (const float*)d_in[10];
  const float* w1  = (const float*)d_in[11];
  const float* b1  = (const float*)d_in[12];
  const float* g1  = (const float*)d_in[13];
  const float* be1 = (const float*)d_in[14];
  const float* w2  = (const float*)d_in[15];
  const float* b2  = (const float*)d_in[16];
  const float* g2  = (const float*)d_in[17];
  const float* be2 = (const float*)d_in[18];
  float* out = (float*)d_out;

  char* ws = (char*)d_ws;
  unsigned int* mask = (unsigned int*)ws;                          // 2 MB
  size_t off = (size_t)N_NODES * MWORDS * 4;
  short* wt_hi = (short*)(ws + off); off += (size_t)1536 * GK * 2; // 768 KB
  short* wt_lo = (short*)(ws + off); off += (size_t)1536 * GK * 2; // 768 KB
  float* bqkv  = (float*)(ws + off); off += 768 * 4;
  float* stats = (float*)(ws + off); off += 2048 * 4;
  off = (off + 255) & ~(size_t)255;
  float* qkv  = (float*)(ws + off); off += (size_t)N_NODES * 768 * 4;  // 12 MB
  float* vagg = (float*)(ws + off); off += (size_t)N_NODES * DIM * 4;
  float* a1   = (float*)(ws + off); off += (size_t)N_NODES * DIM * 4;
  float* h1   = (float*)(ws + off); off += (size_t)N_NODES * DIM * 4;
  float* h2   = (float*)(ws + off); off += (size_t)N_NODES * DIM * 4;

  float* sum1 = stats;
  float* sq1  = stats + 256;
  float* sum2 = stats + 512;
  float* sq2  = stats + 768;
  float* sc1  = stats + 1024;
  float* sh1  = stats + 1280;
  float* sc2  = stats + 1536;
  float* sh2  = stats + 1792;

  const int E = in_sizes[1] / 2;

  hipMemsetAsync(mask, 0, (size_t)N_NODES * MWORDS * 4, stream);
  hipMemsetAsync(stats, 0, 1024 * 4, stream);
  build_mask_kernel<<<(E + 255) / 256, 256, 0, stream>>>(ei, mask, E);
  prep_weights<<<1536, 256, 0, stream>>>(wq, wk, wv, wo, w1, w2, bq, bk, bv,
                                         wt_hi, wt_lo, bqkv);

  // fused QKV projection: [4096,256] @ [256,768]
  dim3 gq(768 / 64, N_NODES / 64);
  gemm_mfma<0><<<gq, 256, 0, stream>>>(x, wt_hi, wt_lo, bqkv, qkv, 768,
                                       nullptr, nullptr, nullptr, nullptr);

  attn_kernel<<<N_NODES / 4, 256, 0, stream>>>(qkv, mask, vagg);

  dim3 gg(DIM / 64, N_NODES / 64);
  // out-projection + eps*x residual
  gemm_mfma<1><<<gg, 256, 0, stream>>>(vagg, wt_hi + (size_t)768 * GK,
                                       wt_lo + (size_t)768 * GK, bo, a1, DIM,
                                       x, eps, nullptr, nullptr);
  // MLP layer 1 pre-activation
  gemm_mfma<0><<<gg, 256, 0, stream>>>(a1, wt_hi + (size_t)1024 * GK,
                                       wt_lo + (size_t)1024 * GK, b1, h1, DIM,
                                       nullptr, nullptr, nullptr, nullptr);
  colstats_kernel<<<64, 256, 0, stream>>>(h1, sum1, sq1);
  bn_finalize_kernel<<<1, 256, 0, stream>>>(sum1, sq1, g1, be1, sc1, sh1);
  // MLP layer 2 with fused BN1+ReLU on the A operand
  gemm_mfma<2><<<gg, 256, 0, stream>>>(h1, wt_hi + (size_t)1280 * GK,
                                       wt_lo + (size_t)1280 * GK, b2, h2, DIM,
                                       nullptr, nullptr, sc1, sh1);
  colstats_kernel<<<64, 256, 0, stream>>>(h2, sum2, sq2);
  bn_finalize_kernel<<<1, 256, 0, stream>>>(sum2, sq2, g2, be2, sc2, sh2);
  // final BN2 + ReLU -> output
  bn_apply_kernel<<<(N_NODES * DIM / 4) / 256, 256, 0, stream>>>(h2, sc2, sh2, out);
}

// Round 4
// 166.843 us; speedup vs baseline: 1.5153x; 1.0793x over previous
//
#include <hip/hip_runtime.h>
#include <math.h>

#define N_NODES 4096
#define DIM 256
#define GK 256        // all GEMM K dims are 256
#define MWORDS 128    // 4096 bits / 32
#define MAXNBR 192    // max in-degree bound (mean 33, std ~5.7, max~55)

typedef float f32x4 __attribute__((ext_vector_type(4)));
typedef short s16x8 __attribute__((ext_vector_type(8)));
typedef short s16x4 __attribute__((ext_vector_type(4)));

__device__ __forceinline__ unsigned short bf16_rne(float f) {
  unsigned int u = __float_as_uint(f);
  u += 0x7FFFu + ((u >> 16) & 1u);
  return (unsigned short)(u >> 16);
}

__device__ __forceinline__ void split_bf16(float f, short& hi, short& lo) {
  unsigned short h = bf16_rne(f);
  float hf = __uint_as_float(((unsigned int)h) << 16);
  hi = (short)h;
  lo = (short)bf16_rne(f - hf);
}

// LDS XOR swizzle: col/row in shorts, pitch 64 shorts (128 B). Flips bits 3-5
// of the short-index -> bank = ((col^s)/2)%32, 16 consecutive rows at fixed
// col cover 8 banks x 2 = free 2-way.
__device__ __forceinline__ int swz(int row, int col) {
  return row * 64 + (col ^ ((row & 7) << 3));
}

// ---------------------------------------------------------------------------
// Fused prep: [0,nmb) edge scatter -> bitmask; [nmb, nmb+1536) weight
// hi/lo split with coalesced writes; last block zeroes BN stat accumulators.
// Weight layout out: Wt[n][k] bf16, QKV rows 0..767, wo 768, w1 1024, w2 1280.
// ---------------------------------------------------------------------------
__global__ void prep_kernel(const int* __restrict__ ei, int E, int nmb,
                            unsigned int* __restrict__ mask,
                            const float* __restrict__ wq, const float* __restrict__ wk,
                            const float* __restrict__ wv, const float* __restrict__ wo,
                            const float* __restrict__ w1, const float* __restrict__ w2,
                            const float* __restrict__ bq, const float* __restrict__ bk,
                            const float* __restrict__ bv,
                            short* __restrict__ wt_hi, short* __restrict__ wt_lo,
                            float* __restrict__ bqkv, float* __restrict__ stats) {
  const int b = blockIdx.x;
  const int t = threadIdx.x;
  if (b < nmb) {  // ---- edge scatter ----
    const int e = b * 256 + t;
    if (e < E) {
      const int r = ei[e];       // destination row
      const int c = ei[E + e];   // source col
      atomicOr(&mask[(size_t)r * MWORDS + (c >> 5)], 1u << (c & 31));
    }
    return;
  }
  const int b2 = b - nmb;
  if (b2 < 1536) {  // ---- weight split: block = output row n, thread = k ----
    const int mat = b2 >> 8;
    const int n = b2 & 255;
    const float* src = (mat == 0) ? wq : (mat == 1) ? wk : (mat == 2) ? wv
                     : (mat == 3) ? wo : (mat == 4) ? w1 : w2;
    const float v = src[(size_t)t * 256 + n];  // strided read, L2-resident
    short hi, lo;
    split_bf16(v, hi, lo);
    const int nbase = (mat < 3) ? mat * 256 : 768 + (mat - 3) * 256;
    const size_t idx = (size_t)(nbase + n) * GK + t;  // coalesced write
    wt_hi[idx] = hi;
    wt_lo[idx] = lo;
    if (t == 0 && mat < 3)
      bqkv[mat * 256 + n] = (mat == 0 ? bq : mat == 1 ? bk : bv)[n];
    return;
  }
  // ---- zero BN stat accumulators (sum1,sq1,sum2,sq2 = 1024 floats) ----
  stats[t] = 0.f;
  stats[t + 256] = 0.f;
  stats[t + 512] = 0.f;
  stats[t + 768] = 0.f;
}

// ---------------------------------------------------------------------------
// MFMA GEMM: C[4096,N] = A[4096,256] @ W[256,N] + bias, bf16 hi/lo 3-term
// split (hh + hl + lh ~ 1e-5 rel err). 4 waves, 2x2 of 32x32 per wave pair.
// EPI 0: bias; EPI 1: bias + eps*X residual; EPI 2: A-side BN+ReLU.
// BN_IN:     compute BN scale/shift from raw sums in prologue (for EPI 2).
// STATS_OUT: column sum/sumsq of the stored C via shfl-reduce + atomics.
// ---------------------------------------------------------------------------
template <int EPI, bool BN_IN, bool STATS_OUT>
__launch_bounds__(256)
__global__ void gemm_mfma(const float* __restrict__ A,
                          const short* __restrict__ Wt_hi,
                          const short* __restrict__ Wt_lo,
                          const float* __restrict__ bias,
                          float* __restrict__ C, int ldc,
                          const float* __restrict__ X,
                          const float* __restrict__ epsp,
                          const float* __restrict__ bnsum,
                          const float* __restrict__ bnsq,
                          const float* __restrict__ bng,
                          const float* __restrict__ bnbe,
                          float* __restrict__ osum,
                          float* __restrict__ osq) {
  __shared__ short As_hi[64 * 64], As_lo[64 * 64];  // pitch 64, XOR-swizzled
  __shared__ short Bs_hi[64 * 64], Bs_lo[64 * 64];
  __shared__ __align__(16) float bnsc[256], bnsh[256];
  __shared__ float redS[2][2][16], redQ[2][2][16];

  const int tid = threadIdx.x;
  const int lane = tid & 63;
  const int wave = tid >> 6;
  const int wr = wave >> 1, wc = wave & 1;
  const int m0 = blockIdx.y * 64;
  const int n0 = blockIdx.x * 64;
  const int l15 = lane & 15;
  const int lg = lane >> 4;  // 0..3

  if (BN_IN) {
    const float invn = 1.f / (float)N_NODES;
    const float mu = bnsum[tid] * invn;
    const float var = bnsq[tid] * invn - mu * mu;
    const float s = bng[tid] * rsqrtf(var + 1e-5f);
    bnsc[tid] = s;
    bnsh[tid] = fmaf(-mu, s, bnbe[tid]);
  }

  f32x4 acc[2][2] = {};

  for (int kt = 0; kt < GK; kt += 64) {
    __syncthreads();
    // ---- stage A: 64m x 64k f32 -> bf16 hi/lo ----
#pragma unroll
    for (int i = 0; i < 4; ++i) {
      const int row = (tid >> 4) + i * 16;
      const int kc = (tid & 15) * 4;
      float4 av = *(const float4*)(A + (size_t)(m0 + row) * GK + kt + kc);
      if (EPI == 2) {
        const float4 s4 = *(const float4*)&bnsc[kt + kc];
        const float4 h4 = *(const float4*)&bnsh[kt + kc];
        av.x = fmaxf(fmaf(av.x, s4.x, h4.x), 0.f);
        av.y = fmaxf(fmaf(av.y, s4.y, h4.y), 0.f);
        av.z = fmaxf(fmaf(av.z, s4.z, h4.z), 0.f);
        av.w = fmaxf(fmaf(av.w, s4.w, h4.w), 0.f);
      }
      short h0, l0, h1, l1, h2, l2, h3, l3;
      split_bf16(av.x, h0, l0);
      split_bf16(av.y, h1, l1);
      split_bf16(av.z, h2, l2);
      split_bf16(av.w, h3, l3);
      s16x4 hv = {h0, h1, h2, h3};
      s16x4 lv = {l0, l1, l2, l3};
      const int o = swz(row, kc);
      *(s16x4*)&As_hi[o] = hv;
      *(s16x4*)&As_lo[o] = lv;
    }
    // ---- stage B: 64n x 64k bf16 ----
#pragma unroll
    for (int i = 0; i < 2; ++i) {
      const int row = (tid >> 3) + i * 32;
      const int kc = (tid & 7) * 8;
      s16x8 bh = *(const s16x8*)(Wt_hi + (size_t)(n0 + row) * GK + kt + kc);
      s16x8 bl = *(const s16x8*)(Wt_lo + (size_t)(n0 + row) * GK + kt + kc);
      const int o = swz(row, kc);
      *(s16x8*)&Bs_hi[o] = bh;
      *(s16x8*)&Bs_lo[o] = bl;
    }
    __syncthreads();
    // ---- MFMA: 2 k-chunks of 32, 2x2 fragments, 3 split terms ----
#pragma unroll
    for (int kk = 0; kk < 2; ++kk) {
      s16x8 ah[2], al[2], bh[2], bl[2];
#pragma unroll
      for (int f = 0; f < 2; ++f) {
        const int ao = swz(wr * 32 + f * 16 + l15, kk * 32 + lg * 8);
        const int bo = swz(wc * 32 + f * 16 + l15, kk * 32 + lg * 8);
        ah[f] = *(const s16x8*)&As_hi[ao];
        al[f] = *(const s16x8*)&As_lo[ao];
        bh[f] = *(const s16x8*)&Bs_hi[bo];
        bl[f] = *(const s16x8*)&Bs_lo[bo];
      }
#pragma unroll
      for (int fm = 0; fm < 2; ++fm)
#pragma unroll
        for (int fn = 0; fn < 2; ++fn) {
          acc[fm][fn] = __builtin_amdgcn_mfma_f32_16x16x32_bf16(ah[fm], bh[fn], acc[fm][fn], 0, 0, 0);
          acc[fm][fn] = __builtin_amdgcn_mfma_f32_16x16x32_bf16(ah[fm], bl[fn], acc[fm][fn], 0, 0, 0);
          acc[fm][fn] = __builtin_amdgcn_mfma_f32_16x16x32_bf16(al[fm], bh[fn], acc[fm][fn], 0, 0, 0);
        }
    }
  }

  // ---- epilogue: D layout col=lane&15, row=(lane>>4)*4+reg ----
  const float ev = (EPI == 1) ? epsp[0] : 0.f;
  float ps[2] = {0.f, 0.f}, pq[2] = {0.f, 0.f};
#pragma unroll
  for (int fm = 0; fm < 2; ++fm) {
    const int row0 = m0 + wr * 32 + fm * 16 + lg * 4;
#pragma unroll
    for (int fn = 0; fn < 2; ++fn) {
      const int col = n0 + wc * 32 + fn * 16 + l15;
      const float bb = bias[col];
#pragma unroll
      for (int j = 0; j < 4; ++j) {
        float v = acc[fm][fn][j] + bb;
        if (EPI == 1) v = fmaf(ev, X[(size_t)(row0 + j) * DIM + col], v);
        C[(size_t)(row0 + j) * ldc + col] = v;
        if (STATS_OUT) {
          ps[fn] += v;
          pq[fn] = fmaf(v, v, pq[fn]);
        }
      }
    }
  }
  if (STATS_OUT) {
#pragma unroll
    for (int fn = 0; fn < 2; ++fn) {
      ps[fn] += __shfl_xor(ps[fn], 16);
      ps[fn] += __shfl_xor(ps[fn], 32);
      pq[fn] += __shfl_xor(pq[fn], 16);
      pq[fn] += __shfl_xor(pq[fn], 32);
    }
    if (wr == 1 && lane < 16) {
      redS[wc][0][l15] = ps[0];
      redS[wc][1][l15] = ps[1];
      redQ[wc][0][l15] = pq[0];
      redQ[wc][1][l15] = pq[1];
    }
    __syncthreads();
    if (wr == 0 && lane < 16) {
#pragma unroll
      for (int fn = 0; fn < 2; ++fn) {
        const int col = n0 + wc * 32 + fn * 16 + l15;
        atomicAdd(&osum[col], ps[fn] + redS[wc][fn][l15]);
        atomicAdd(&osq[col], pq[fn] + redQ[wc][fn][l15]);
      }
    }
  }
}

// ---------------------------------------------------------------------------
// Sparse attention, one wave per destination row.
// Phase 1: cooperative neighbor extraction into LDS CSR.
// Phase 2: batches of 8 edges -> 16 independent b128 gathers in flight.
// Lanes 0-31 = head 0 (dims 0-127), lanes 32-63 = head 1.
// ---------------------------------------------------------------------------
__launch_bounds__(256)
__global__ void attn_kernel(const float* __restrict__ qkv,
                            const unsigned int* __restrict__ mask,
                            float* __restrict__ vagg) {
  __shared__ int nbr[4][MAXNBR];
  const int wave = threadIdx.x >> 6;
  const int lane = threadIdx.x & 63;
  const int r = blockIdx.x * 4 + wave;

  // ---- phase 1: extract neighbor list ----
  const unsigned int* mrow = mask + (size_t)r * MWORDS;
  int total = 0;
#pragma unroll
  for (int round = 0; round < 2; ++round) {
    unsigned int w = mrow[round * 64 + lane];
    const int cnt = __popc(w);
    int pre = cnt;
#pragma unroll
    for (int off = 1; off < 64; off <<= 1) {
      int tt = __shfl_up(pre, off);
      if (lane >= off) pre += tt;
    }
    const int wtot = __shfl(pre, 63);
    pre -= cnt;  // exclusive
    int base = total + pre;
    while (w) {
      const int b = __ffs(w) - 1;
      w &= w - 1;
      nbr[wave][base++] = (round * 64 + lane) * 32 + b;
    }
    total += wtot;
  }

  // ---- phase 2: online softmax, batches of 8 ----
  float4 q = *(const float4*)(qkv + (size_t)r * 768 + lane * 4);
  const float sc = 0.088388347648318447f;  // 1/sqrt(128)
  q.x *= sc; q.y *= sc; q.z *= sc; q.w *= sc;

  float4 acc = make_float4(0.f, 0.f, 0.f, 0.f);
  float m = -INFINITY, lsum = 0.f;
  const int* nb = nbr[wave];

  for (int i = 0; i < total; i += 8) {
    int cs[8];
    float4 kf[8], vf[8];
    float d[8];
#pragma unroll
    for (int j = 0; j < 8; ++j)
      cs[j] = (i + j < total) ? nb[i + j] : -1;
#pragma unroll
    for (int j = 0; j < 8; ++j) {
      const float* p = qkv + (size_t)(cs[j] < 0 ? cs[0] : cs[j]) * 768 + lane * 4;
      kf[j] = *(const float4*)(p + 256);
      vf[j] = *(const float4*)(p + 512);
    }
#pragma unroll
    for (int j = 0; j < 8; ++j)
      d[j] = q.x * kf[j].x + q.y * kf[j].y + q.z * kf[j].z + q.w * kf[j].w;
#pragma unroll
    for (int s = 16; s >= 1; s >>= 1)
#pragma unroll
      for (int j = 0; j < 8; ++j) d[j] += __shfl_xor(d[j], s);
#pragma unroll
    for (int j = 1; j < 8; ++j)
      if (cs[j] < 0) d[j] = -INFINITY;
    float mnew = m;
#pragma unroll
    for (int j = 0; j < 8; ++j) mnew = fmaxf(mnew, d[j]);
    const float resc = __expf(m - mnew);  // first iter: exp(-inf)=0
    float e[8];
    float esum = 0.f;
#pragma unroll
    for (int j = 0; j < 8; ++j) {
      e[j] = __expf(d[j] - mnew);
      esum += e[j];
    }
    lsum = lsum * resc + esum;
    float ax = acc.x * resc, ay = acc.y * resc, az = acc.z * resc, aw = acc.w * resc;
#pragma unroll
    for (int j = 0; j < 8; ++j) {
      ax = fmaf(e[j], vf[j].x, ax);
      ay = fmaf(e[j], vf[j].y, ay);
      az = fmaf(e[j], vf[j].z, az);
      aw = fmaf(e[j], vf[j].w, aw);
    }
    acc.x = ax; acc.y = ay; acc.z = az; acc.w = aw;
    m = mnew;
  }
  const float inv = 1.f / lsum;
  float4 o = make_float4(acc.x * inv, acc.y * inv, acc.z * inv, acc.w * inv);
  *(float4*)(vagg + (size_t)r * DIM + lane * 4) = o;
}

// ---------------------------------------------------------------------------
// Final BN2 + ReLU with in-kernel finalize: each thread owns 4 fixed columns
// (col = 4t & 255, invariant across grid-stride iters) -> reg scale/shift.
// ---------------------------------------------------------------------------
__launch_bounds__(256)
__global__ void bn_apply_final(const float* __restrict__ H,
                               const float* __restrict__ sum,
                               const float* __restrict__ sumsq,
                               const float* __restrict__ g,
                               const float* __restrict__ be,
                               float* __restrict__ out) {
  const int t = threadIdx.x;
  const int c0 = (t * 4) & (DIM - 1);
  const float invn = 1.f / (float)N_NODES;
  float4 s4 = *(const float4*)&sum[c0];
  float4 q4 = *(const float4*)&sumsq[c0];
  float4 g4 = *(const float4*)&g[c0];
  float4 b4 = *(const float4*)&be[c0];
  float scl[4], shf[4];
#pragma unroll
  for (int j = 0; j < 4; ++j) {
    const float mu = ((const float*)&s4)[j] * invn;
    const float var = ((const float*)&q4)[j] * invn - mu * mu;
    const float s = ((const float*)&g4)[j] * rsqrtf(var + 1e-5f);
    scl[j] = s;
    shf[j] = fmaf(-mu, s, ((const float*)&b4)[j]);
  }
  const int stride = gridDim.x * 256;
  for (int i = blockIdx.x * 256 + t; i < N_NODES * DIM / 4; i += stride) {
    const float4 h = ((const float4*)H)[i];
    float4 o;
    o.x = fmaxf(fmaf(h.x, scl[0], shf[0]), 0.f);
    o.y = fmaxf(fmaf(h.y, scl[1], shf[1]), 0.f);
    o.z = fmaxf(fmaf(h.z, scl[2], shf[2]), 0.f);
    o.w = fmaxf(fmaf(h.w, scl[3], shf[3]), 0.f);
    ((float4*)out)[i] = o;
  }
}

// ---------------------------------------------------------------------------
extern "C" void kernel_launch(void* const* d_in, const int* in_sizes, int n_in,
                              void* d_out, int out_size, void* d_ws, size_t ws_size,
                              hipStream_t stream) {
  const float* x   = (const float*)d_in[0];
  const int*   ei  = (const int*)d_in[1];   // int32 (JAX x64 disabled)
  const float* wq  = (const float*)d_in[2];
  const float* bq  = (const float*)d_in[3];
  const float* wk  = (const float*)d_in[4];
  const float* bk  = (const float*)d_in[5];
  const float* wv  = (const float*)d_in[6];
  const float* bv  = (const float*)d_in[7];
  const float* wo  = (const float*)d_in[8];
  const float* bo  = (const float*)d_in[9];
  const float* eps = (const float*)d_in[10];
  const float* w1  = (const float*)d_in[11];
  const float* b1  = (const float*)d_in[12];
  const float* g1  = (const float*)d_in[13];
  const float* be1 = (const float*)d_in[14];
  const float* w2  = (const float*)d_in[15];
  const float* b2  = (const float*)d_in[16];
  const float* g2  = (const float*)d_in[17];
  const float* be2 = (const float*)d_in[18];
  float* out = (float*)d_out;

  char* ws = (char*)d_ws;
  unsigned int* mask = (unsigned int*)ws;                          // 2 MB
  size_t off = (size_t)N_NODES * MWORDS * 4;
  short* wt_hi = (short*)(ws + off); off += (size_t)1536 * GK * 2; // 768 KB
  short* wt_lo = (short*)(ws + off); off += (size_t)1536 * GK * 2; // 768 KB
  float* bqkv  = (float*)(ws + off); off += 768 * 4;
  float* stats = (float*)(ws + off); off += 1024 * 4;
  off = (off + 255) & ~(size_t)255;
  float* qkv  = (float*)(ws + off); off += (size_t)N_NODES * 768 * 4;  // 12 MB
  float* vagg = (float*)(ws + off); off += (size_t)N_NODES * DIM * 4;
  float* a1   = (float*)(ws + off); off += (size_t)N_NODES * DIM * 4;
  float* h1   = (float*)(ws + off); off += (size_t)N_NODES * DIM * 4;
  float* h2   = (float*)(ws + off); off += (size_t)N_NODES * DIM * 4;

  float* sum1 = stats;
  float* sq1  = stats + 256;
  float* sum2 = stats + 512;
  float* sq2  = stats + 768;

  const int E = in_sizes[1] / 2;
  const int nmb = (E + 255) / 256;

  hipMemsetAsync(mask, 0, (size_t)N_NODES * MWORDS * 4, stream);
  prep_kernel<<<nmb + 1537, 256, 0, stream>>>(ei, E, nmb, mask,
                                              wq, wk, wv, wo, w1, w2,
                                              bq, bk, bv, wt_hi, wt_lo, bqkv, stats);

  // fused QKV projection: [4096,256] @ [256,768]
  dim3 gq(768 / 64, N_NODES / 64);
  gemm_mfma<0, false, false><<<gq, 256, 0, stream>>>(
      x, wt_hi, wt_lo, bqkv, qkv, 768,
      nullptr, nullptr, nullptr, nullptr, nullptr, nullptr, nullptr, nullptr);

  attn_kernel<<<N_NODES / 4, 256, 0, stream>>>(qkv, mask, vagg);

  dim3 gg(DIM / 64, N_NODES / 64);
  // out-projection + eps*x residual
  gemm_mfma<1, false, false><<<gg, 256, 0, stream>>>(
      vagg, wt_hi + (size_t)768 * GK, wt_lo + (size_t)768 * GK, bo, a1, DIM,
      x, eps, nullptr, nullptr, nullptr, nullptr, nullptr, nullptr);
  // MLP layer 1 + column stats
  gemm_mfma<0, false, true><<<gg, 256, 0, stream>>>(
      a1, wt_hi + (size_t)1024 * GK, wt_lo + (size_t)1024 * GK, b1, h1, DIM,
      nullptr, nullptr, nullptr, nullptr, nullptr, nullptr, sum1, sq1);
  // MLP layer 2: BN1 finalize in prologue + ReLU on A, stats out
  gemm_mfma<2, true, true><<<gg, 256, 0, stream>>>(
      h1, wt_hi + (size_t)1280 * GK, wt_lo + (size_t)1280 * GK, b2, h2, DIM,
      nullptr, nullptr, sum1, sq1, g1, be1, sum2, sq2);
  // final BN2 + ReLU -> output (finalize fused)
  bn_apply_final<<<512, 256, 0, stream>>>(h2, sum2, sq2, g2, be2, out);
}